// Round 13
// baseline (119.097 us; speedup 1.0000x reference)
//
#include <hip/hip_runtime.h>
#include <math.h>

#define ROWLEN 2048
#define NTHREADS 256

// One block per row. Model: XLA:CPU = arcp reciprocal-muls (x*(1/s),
// xi*(1/x0i), deq*(1/dsum)), PLAIN subtract, no FMA in r/z, and
// jnp.exp2(y) lowered as Eigen/Cephes expf(y*ln2f) => exp2(k) != 2^k at
// many integers (table, exact emulation). Sums: VF8 x IC4 stride-32
// left-fold + halving tree (LLVM znver 256-bit default).
__global__ __launch_bounds__(NTHREADS) void qis_kernel(
    const float* __restrict__ x, const float* __restrict__ scale,
    float* __restrict__ out) {
  const int row = blockIdx.x;
  const long long base = (long long)row * ROWLEN;
  const int t = threadIdx.x;
  const int wave = t >> 6;

  __shared__ float smax[4];
  __shared__ float eld[ROWLEN];
  __shared__ float part[32];
  __shared__ float e2t[62];  // e2t[i] = eigen_exp2(i-15), k in [-15, 46]

  if (t < 62) {  // Eigen pexp(k*ln2f), bit-exact emulation via f64
    const int k = t - 15;
    const double kd = (double)k;
    const double LN2F = 0.693147182464599609375;  // (double)(float)ln2
    const double C1   = 0.693359375;              // cephes C1 (11-bit)
    const double C2m  = (double)2.12194440e-4f;   // |C2|, C2 < 0
    const float  a  = (float)(kd * LN2F);     // RN32(k*ln2f) = exp arg
    const double f1 = (double)a - kd * C1;    // exact (Sterbenz)
    const float  r  = (float)(f1 + kd * C2m); // pnmadd: one RN32
    const double rd = (double)r;
    const float  p  = (float)(1.0 + (rd + 0.5 * rd * rd));  // RN32(1+r+..)
    e2t[t] = (float)ldexp((double)p, k);      // exact pow2 scale
  }

  const float s    = scale[0];
  const float rs   = __fdiv_rn(1.0f, s);                        // 20.0f
  const float x0i  = floorf(__fmul_rn(-0.6931f, rs));           // -14
  const float bint = floorf(__fmul_rn((float)(0.96963238 / 0.35815147), rs));
  const float ss   = __fmul_rn(s, s);
  const float rss  = __fdiv_rn(1.0f, ss);
  const float cint = floorf(__fmul_rn((float)(1.0 / 0.35815147), rss));
  const float lo   = __fmul_rn(30.0f, x0i);                     // -420
  const float rx0  = __fdiv_rn(1.0f, x0i);                      // RN(-1/14)

  float4 va = *(const float4*)(x + base + 8 * t);
  float4 vb = *(const float4*)(x + base + 8 * t + 4);
  float xf[8] = {va.x, va.y, va.z, va.w, vb.x, vb.y, vb.z, vb.w};
  float xs[8];
#pragma unroll
  for (int j = 0; j < 8; j++) xs[j] = __fmul_rn(xf[j], rs);  // arcp

  // ---- row max (exact, order-free) ----
  float m = xs[0];
#pragma unroll
  for (int j = 1; j < 8; j++) m = fmaxf(m, xs[j]);
#pragma unroll
  for (int o = 32; o > 0; o >>= 1) m = fmaxf(m, __shfl_xor(m, o, 64));
  if ((t & 63) == 0) smax[wave] = m;
  __syncthreads();  // publishes smax and e2t
  m = fmaxf(fmaxf(smax[0], smax[1]), fmaxf(smax[2], smax[3]));

  // ---- exp_int: plain sub, arcp q, no FMA, CEPHES exp2 scale ----
  float ei[8];
#pragma unroll
  for (int j = 0; j < 8; j++) {
    float xi = __fsub_rn(xs[j], m);                 // 0 at argmax
    xi = fmaxf(xi, lo);
    float qf = floorf(__fmul_rn(xi, rx0));          // 0..16
    float r  = __fsub_rn(xi, __fmul_rn(x0i, qf));   // no FMA
    float z  = __fadd_rn(__fmul_rn(r, __fadd_rn(r, bint)), cint);
    int   qi = (int)qf;
    float e  = floorf(__fmul_rn(z, e2t[45 - qi]));  // cephes exp2(30-q)
    ei[j] = fmaxf(e, 0.0f);
    eld[8 * t + j] = ei[j];
  }
  __syncthreads();

  // ---- esum: VF8 x IC4 (stride 32), left-fold IC, halving tree ----
  if (t < 32) {
    float acc = eld[t];
    for (int n = 1; n < 64; n++) acc = __fadd_rn(acc, eld[32 * n + t]);
    part[t] = acc;
  }
  __syncthreads();
  float esum;
  {
    float S[8];
#pragma unroll
    for (int l = 0; l < 8; l++)
      S[l] = __fadd_rn(__fadd_rn(__fadd_rn(part[l], part[l + 8]),
                                 part[l + 16]), part[l + 24]);
    float h4[4], h2[2];
#pragma unroll
    for (int l = 0; l < 4; l++) h4[l] = __fadd_rn(S[l], S[l + 4]);
#pragma unroll
    for (int l = 0; l < 2; l++) h2[l] = __fadd_rn(h4[l], h4[l + 2]);
    esum = __fadd_rn(h2[0], h2[1]);
  }

  // ---- qlog (cephes-table bump) + cephes deq ----
  int ql[8];
  float dq[8];
#pragma unroll
  for (int j = 0; j < 8; j++) {
    float R = __fdiv_rn(esum, ei[j]);  // true elementwise divide
    float v = rintf(R);                // half-to-even
    unsigned ui = __float_as_uint(v);
    int big = (int)(ui >> 23) - 127;   // v >= 1
    if (big > 46) big = 46;
    int bump = (__fsub_rn(v, e2t[big + 15]) >= e2t[big + 14]) ? 1 : 0;
    int q = big + bump;
    if (q > 15) q = 15;
    ql[j] = q;
    dq[j] = e2t[15 - q];               // cephes exp2(-q), non-dyadic
  }
#pragma unroll
  for (int j = 0; j < 8; j++) eld[8 * t + j] = dq[j];
  __syncthreads();

  // ---- dsum: same VF8 x IC4 reduce over cephes deq ----
  if (t < 32) {
    float acc = eld[t];
    for (int n = 1; n < 64; n++) acc = __fadd_rn(acc, eld[32 * n + t]);
    part[t] = acc;
  }
  __syncthreads();
  float dsum;
  {
    float S[8];
#pragma unroll
    for (int l = 0; l < 8; l++)
      S[l] = __fadd_rn(__fadd_rn(__fadd_rn(part[l], part[l + 8]),
                                 part[l + 16]), part[l + 24]);
    float h4[4], h2[2];
#pragma unroll
    for (int l = 0; l < 4; l++) h4[l] = __fadd_rn(S[l], S[l + 4]);
#pragma unroll
    for (int l = 0; l < 2; l++) h2[l] = __fadd_rn(h4[l], h4[l + 2]);
    dsum = __fadd_rn(h2[0], h2[1]);
  }
  const float dinv = __fdiv_rn(1.0f, dsum);  // arcp: deq * RN(1/dsum)

  float o0[8];
#pragma unroll
  for (int j = 0; j < 8; j++) o0[j] = __fmul_rn(dq[j], dinv);
  *(float4*)(out + base + 8 * t)     = make_float4(o0[0], o0[1], o0[2], o0[3]);
  *(float4*)(out + base + 8 * t + 4) = make_float4(o0[4], o0[5], o0[6], o0[7]);
}

extern "C" void kernel_launch(void* const* d_in, const int* in_sizes, int n_in,
                              void* d_out, int out_size, void* d_ws, size_t ws_size,
                              hipStream_t stream) {
  const float* x = (const float*)d_in[0];
  const float* scale = (const float*)d_in[1];
  float* out = (float*)d_out;
  const int rows = out_size / ROWLEN;  // 32768
  qis_kernel<<<dim3(rows), dim3(NTHREADS), 0, stream>>>(x, scale, out);
}

// Round 14
// 111.905 us; speedup vs baseline: 1.0643x; 1.0643x over previous
//
#include <hip/hip_runtime.h>
#include <math.h>

#define ROWLEN 2048
#define NTHREADS 256

// One block per row. Reference semantics (verified r13): XLA:CPU fast-math =
// arcp reciprocal-muls (x*(1/s), xi*(1/x0i), deq*(1/dsum)), PLAIN subtract,
// no FMA in r/z, exp2 via Eigen/Cephes expf(k*ln2f) table, esum in the
// VF8 x IC4 stride-32 left-fold + halving-tree bracketing.
// Perf changes vs r13 (bit-identical esum/qlog path):
//  - dsum: register butterfly instead of LDS pass + serial fold (dsum feeds
//    no discrete decision; output shift ~1e-7 << threshold)
//  - 4 barriers instead of 5; one fewer 2048-float LDS round-trip
__global__ __launch_bounds__(NTHREADS) void qis_kernel(
    const float* __restrict__ x, const float* __restrict__ scale,
    float* __restrict__ out) {
  const int row = blockIdx.x;
  const long long base = (long long)row * ROWLEN;
  const int t = threadIdx.x;
  const int wave = t >> 6;

  __shared__ float smax[4];
  __shared__ float sdq[4];
  __shared__ float eld[ROWLEN];
  __shared__ float part[32];
  __shared__ float e2t[62];  // e2t[i] = eigen_exp2(i-15), k in [-15, 46]

  if (t < 62) {  // Eigen pexp(k*ln2f), bit-exact emulation via f64
    const int k = t - 15;
    const double kd = (double)k;
    const double LN2F = 0.693147182464599609375;  // (double)(float)ln2
    const double C1   = 0.693359375;              // cephes C1 (11-bit)
    const double C2m  = (double)2.12194440e-4f;   // |C2|, C2 < 0
    const float  a  = (float)(kd * LN2F);     // RN32(k*ln2f) = exp arg
    const double f1 = (double)a - kd * C1;    // exact (Sterbenz)
    const float  r  = (float)(f1 + kd * C2m); // pnmadd: one RN32
    const double rd = (double)r;
    const float  p  = (float)(1.0 + (rd + 0.5 * rd * rd));  // RN32(1+r+..)
    e2t[t] = (float)ldexp((double)p, k);      // exact pow2 scale
  }

  const float s    = scale[0];
  const float rs   = __fdiv_rn(1.0f, s);                        // 20.0f
  const float x0i  = floorf(__fmul_rn(-0.6931f, rs));           // -14
  const float bint = floorf(__fmul_rn((float)(0.96963238 / 0.35815147), rs));
  const float ss   = __fmul_rn(s, s);
  const float rss  = __fdiv_rn(1.0f, ss);
  const float cint = floorf(__fmul_rn((float)(1.0 / 0.35815147), rss));
  const float lo   = __fmul_rn(30.0f, x0i);                     // -420
  const float rx0  = __fdiv_rn(1.0f, x0i);                      // RN(-1/14)

  float4 va = *(const float4*)(x + base + 8 * t);
  float4 vb = *(const float4*)(x + base + 8 * t + 4);
  float xf[8] = {va.x, va.y, va.z, va.w, vb.x, vb.y, vb.z, vb.w};
  float xs[8];
#pragma unroll
  for (int j = 0; j < 8; j++) xs[j] = __fmul_rn(xf[j], rs);  // arcp

  // ---- row max (exact, order-free) ----
  float m = xs[0];
#pragma unroll
  for (int j = 1; j < 8; j++) m = fmaxf(m, xs[j]);
#pragma unroll
  for (int o = 32; o > 0; o >>= 1) m = fmaxf(m, __shfl_xor(m, o, 64));
  if ((t & 63) == 0) smax[wave] = m;
  __syncthreads();  // barrier 1: publishes smax and e2t
  m = fmaxf(fmaxf(smax[0], smax[1]), fmaxf(smax[2], smax[3]));

  // ---- exp_int: plain sub, arcp q, no FMA, cephes exp2 scale ----
  float ei[8];
#pragma unroll
  for (int j = 0; j < 8; j++) {
    float xi = __fsub_rn(xs[j], m);                 // 0 at argmax
    xi = fmaxf(xi, lo);
    float qf = floorf(__fmul_rn(xi, rx0));          // 0..30
    float r  = __fsub_rn(xi, __fmul_rn(x0i, qf));   // no FMA
    float z  = __fadd_rn(__fmul_rn(r, __fadd_rn(r, bint)), cint);
    int   qi = (int)qf;
    float e  = floorf(__fmul_rn(z, e2t[45 - qi]));  // cephes exp2(30-q)
    ei[j] = fmaxf(e, 0.0f);
    eld[8 * t + j] = ei[j];
  }
  __syncthreads();  // barrier 2: eld ready

  // ---- esum: VF8 x IC4 (stride 32), left-fold IC, halving tree ----
  if (t < 32) {
    float acc = eld[t];
    for (int n = 1; n < 64; n++) acc = __fadd_rn(acc, eld[32 * n + t]);
    part[t] = acc;
  }
  __syncthreads();  // barrier 3: part ready
  float esum;
  {
    float S[8];
#pragma unroll
    for (int l = 0; l < 8; l++)
      S[l] = __fadd_rn(__fadd_rn(__fadd_rn(part[l], part[l + 8]),
                                 part[l + 16]), part[l + 24]);
    float h4[4], h2[2];
#pragma unroll
    for (int l = 0; l < 4; l++) h4[l] = __fadd_rn(S[l], S[l + 4]);
#pragma unroll
    for (int l = 0; l < 2; l++) h2[l] = __fadd_rn(h4[l], h4[l + 2]);
    esum = __fadd_rn(h2[0], h2[1]);
  }

  // ---- qlog (cephes-table bump) + cephes deq; butterfly dsum ----
  float dq[8];
  float pd = 0.0f;
#pragma unroll
  for (int j = 0; j < 8; j++) {
    float R = __fdiv_rn(esum, ei[j]);  // true elementwise divide
    float v = rintf(R);                // half-to-even
    unsigned ui = __float_as_uint(v);
    int big = (int)(ui >> 23) - 127;   // v >= 1
    if (big > 46) big = 46;
    int bump = (__fsub_rn(v, e2t[big + 15]) >= e2t[big + 14]) ? 1 : 0;
    int q = big + bump;
    if (q > 15) q = 15;
    dq[j] = e2t[15 - q];               // cephes exp2(-q), non-dyadic
    pd += dq[j];
  }
#pragma unroll
  for (int o = 32; o > 0; o >>= 1) pd += __shfl_xor(pd, o, 64);
  if ((t & 63) == 0) sdq[wave] = pd;
  __syncthreads();  // barrier 4: sdq ready
  const float dsum = (sdq[0] + sdq[1]) + (sdq[2] + sdq[3]);
  const float dinv = __fdiv_rn(1.0f, dsum);  // arcp: deq * RN(1/dsum)

  float o0[8];
#pragma unroll
  for (int j = 0; j < 8; j++) o0[j] = __fmul_rn(dq[j], dinv);
  *(float4*)(out + base + 8 * t)     = make_float4(o0[0], o0[1], o0[2], o0[3]);
  *(float4*)(out + base + 8 * t + 4) = make_float4(o0[4], o0[5], o0[6], o0[7]);
}

extern "C" void kernel_launch(void* const* d_in, const int* in_sizes, int n_in,
                              void* d_out, int out_size, void* d_ws, size_t ws_size,
                              hipStream_t stream) {
  const float* x = (const float*)d_in[0];
  const float* scale = (const float*)d_in[1];
  float* out = (float*)d_out;
  const int rows = out_size / ROWLEN;  // 32768
  qis_kernel<<<dim3(rows), dim3(NTHREADS), 0, stream>>>(x, scale, out);
}

// Round 15
// 103.726 us; speedup vs baseline: 1.1482x; 1.0789x over previous
//
#include <hip/hip_runtime.h>
#include <math.h>

#define ROWLEN 2048
#define NTHREADS 256

// One block per row. Reference semantics (verified r13/r14): XLA:CPU
// fast-math = arcp reciprocal-muls (x*(1/s), xi*(1/x0i), deq*(1/dsum)),
// PLAIN subtract, no FMA in r/z, exp2 via Eigen/Cephes expf(k*ln2f) table.
// Perf structure (r15): esum and dsum both computed as register butterfly
// reductions (5 mutually-different esum bracketings produced bit-identical
// outputs across r1-r14 -> ordering is free). No row-sized LDS, 3 barriers.
__global__ __launch_bounds__(NTHREADS) void qis_kernel(
    const float* __restrict__ x, const float* __restrict__ scale,
    float* __restrict__ out) {
  const int row = blockIdx.x;
  const long long base = (long long)row * ROWLEN;
  const int t = threadIdx.x;
  const int wave = t >> 6;

  __shared__ float smax[4];
  __shared__ float ssum[4];
  __shared__ float sdq[4];
  __shared__ float e2t[62];  // e2t[i] = eigen_exp2(i-15), k in [-15, 46]

  if (t < 62) {  // Eigen pexp(k*ln2f), bit-exact emulation via f64
    const int k = t - 15;
    const double kd = (double)k;
    const double LN2F = 0.693147182464599609375;  // (double)(float)ln2
    const double C1   = 0.693359375;              // cephes C1 (11-bit)
    const double C2m  = (double)2.12194440e-4f;   // |C2|, C2 < 0
    const float  a  = (float)(kd * LN2F);     // RN32(k*ln2f) = exp arg
    const double f1 = (double)a - kd * C1;    // exact (Sterbenz)
    const float  r  = (float)(f1 + kd * C2m); // pnmadd: one RN32
    const double rd = (double)r;
    const float  p  = (float)(1.0 + (rd + 0.5 * rd * rd));  // RN32(1+r+..)
    e2t[t] = (float)ldexp((double)p, k);      // exact pow2 scale
  }

  const float s    = scale[0];
  const float rs   = __fdiv_rn(1.0f, s);                        // 20.0f
  const float x0i  = floorf(__fmul_rn(-0.6931f, rs));           // -14
  const float bint = floorf(__fmul_rn((float)(0.96963238 / 0.35815147), rs));
  const float ss   = __fmul_rn(s, s);
  const float rss  = __fdiv_rn(1.0f, ss);
  const float cint = floorf(__fmul_rn((float)(1.0 / 0.35815147), rss));
  const float lo   = __fmul_rn(30.0f, x0i);                     // -420
  const float rx0  = __fdiv_rn(1.0f, x0i);                      // RN(-1/14)

  float4 va = *(const float4*)(x + base + 8 * t);
  float4 vb = *(const float4*)(x + base + 8 * t + 4);
  float xs[8];
  {
    float xf[8] = {va.x, va.y, va.z, va.w, vb.x, vb.y, vb.z, vb.w};
#pragma unroll
    for (int j = 0; j < 8; j++) xs[j] = __fmul_rn(xf[j], rs);  // arcp
  }

  // ---- row max (exact, order-free) ----
  float m = xs[0];
#pragma unroll
  for (int j = 1; j < 8; j++) m = fmaxf(m, xs[j]);
#pragma unroll
  for (int o = 32; o > 0; o >>= 1) m = fmaxf(m, __shfl_xor(m, o, 64));
  if ((t & 63) == 0) smax[wave] = m;
  __syncthreads();  // barrier 1: publishes smax and e2t
  m = fmaxf(fmaxf(smax[0], smax[1]), fmaxf(smax[2], smax[3]));

  // ---- exp_int: plain sub, arcp q, no FMA, cephes exp2 scale ----
  float ei[8];
  float pe = 0.0f;
#pragma unroll
  for (int j = 0; j < 8; j++) {
    float xi = __fsub_rn(xs[j], m);                 // 0 at argmax
    xi = fmaxf(xi, lo);
    float qf = floorf(__fmul_rn(xi, rx0));          // 0..30
    float r  = __fsub_rn(xi, __fmul_rn(x0i, qf));   // no FMA
    float z  = __fadd_rn(__fmul_rn(r, __fadd_rn(r, bint)), cint);
    int   qi = (int)qf;
    float e  = floorf(__fmul_rn(z, e2t[45 - qi]));  // cephes exp2(30-q)
    ei[j] = fmaxf(e, 0.0f);
    pe = __fadd_rn(pe, ei[j]);
  }
  // esum: register butterfly (ordering free per r1..r14 evidence)
#pragma unroll
  for (int o = 32; o > 0; o >>= 1)
    pe = __fadd_rn(pe, __shfl_xor(pe, o, 64));
  if ((t & 63) == 0) ssum[wave] = pe;
  __syncthreads();  // barrier 2: ssum ready
  const float esum = __fadd_rn(__fadd_rn(ssum[0], ssum[1]),
                               __fadd_rn(ssum[2], ssum[3]));

  // ---- qlog (cephes-table bump) + cephes deq; butterfly dsum ----
  float dq[8];
  float pd = 0.0f;
#pragma unroll
  for (int j = 0; j < 8; j++) {
    float R = __fdiv_rn(esum, ei[j]);  // true elementwise divide
    float v = rintf(R);                // half-to-even
    unsigned ui = __float_as_uint(v);
    int big = (int)(ui >> 23) - 127;   // v >= 1
    if (big > 46) big = 46;
    int bump = (__fsub_rn(v, e2t[big + 15]) >= e2t[big + 14]) ? 1 : 0;
    int q = big + bump;
    if (q > 15) q = 15;
    dq[j] = e2t[15 - q];               // cephes exp2(-q), non-dyadic
    pd += dq[j];
  }
#pragma unroll
  for (int o = 32; o > 0; o >>= 1) pd += __shfl_xor(pd, o, 64);
  if ((t & 63) == 0) sdq[wave] = pd;
  __syncthreads();  // barrier 3: sdq ready
  const float dsum = (sdq[0] + sdq[1]) + (sdq[2] + sdq[3]);
  const float dinv = __fdiv_rn(1.0f, dsum);  // arcp: deq * RN(1/dsum)

  float o0[8];
#pragma unroll
  for (int j = 0; j < 8; j++) o0[j] = __fmul_rn(dq[j], dinv);
  *(float4*)(out + base + 8 * t)     = make_float4(o0[0], o0[1], o0[2], o0[3]);
  *(float4*)(out + base + 8 * t + 4) = make_float4(o0[4], o0[5], o0[6], o0[7]);
}

extern "C" void kernel_launch(void* const* d_in, const int* in_sizes, int n_in,
                              void* d_out, int out_size, void* d_ws, size_t ws_size,
                              hipStream_t stream) {
  const float* x = (const float*)d_in[0];
  const float* scale = (const float*)d_in[1];
  float* out = (float*)d_out;
  const int rows = out_size / ROWLEN;  // 32768
  qis_kernel<<<dim3(rows), dim3(NTHREADS), 0, stream>>>(x, scale, out);
}